// Round 5
// baseline (252.452 us; speedup 1.0000x reference)
//
#include <hip/hip_runtime.h>
#include <math.h>

// Problem constants
#define D 64
#define HWD 4096          // 64*64
#define NVEC 131072       // 32*64*64
#define K 1024

// d_out layout (float element offsets: loss, out, perplexity, encodings, inputs)
#define O_LOSS 0
#define O_OUT  1
#define O_PERP 8388609ULL
#define O_ENC  8388610ULL
#define O_INP  142606338ULL   // 8388610 + 134217728

// d_ws layout (bytes)
#define WS_CBH   0          // K*D fp16 B-fragment-packed (131072 B)
#define WS_CBL   131072     // K*D fp16 lo part           (131072 B)
#define WS_C2    262144     // 1024 float                 (4096 B)
#define WS_HIST  266240     // 1024 int                   (4096 B)
#define WS_LPART 270336     // 2048 float                 (8192 B)

typedef _Float16 half8 __attribute__((ext_vector_type(8)));
typedef float    f32x16 __attribute__((ext_vector_type(16)));
typedef float    f32x4  __attribute__((ext_vector_type(4)));

// ---------------------------------------------------------------------------
// Fused prep: blocks 0-31 pack codebook into MFMA B-fragment layout (fp16
// hi/lo); blocks 32-35 compute ||c||^2 (fp32 exact).
// unit u = (kt*4 + s)*64 + lane; lane holds code k = kt*32+(lane&31),
// d = s*16 + (lane>>5)*8 + i  (v_mfma_f32_32x32x16_f16 B layout).
__global__ __launch_bounds__(256) void prep_kernel(const float* __restrict__ cb,
                                                   _Float16* __restrict__ cbh,
                                                   _Float16* __restrict__ cbl,
                                                   float* __restrict__ c2) {
    if (blockIdx.x < 32) {
        int u  = blockIdx.x * 256 + threadIdx.x;   // 8192 units
        int l  = u & 63;
        int s  = (u >> 6) & 3;
        int kt = u >> 8;
        int k  = kt * 32 + (l & 31);
        int d0 = s * 16 + (l >> 5) * 8;
        const float* src = cb + k * D + d0;
        half8 h, lo;
        #pragma unroll
        for (int i = 0; i < 8; ++i) {
            float v = src[i];
            _Float16 hh = (_Float16)v;
            h[i]  = hh;
            lo[i] = (_Float16)(v - (float)hh);
        }
        reinterpret_cast<half8*>(cbh)[u] = h;
        reinterpret_cast<half8*>(cbl)[u] = lo;
    } else {
        int k = (blockIdx.x - 32) * 256 + threadIdx.x;
        const float4* row = reinterpret_cast<const float4*>(cb + k * D);
        float s = 0.f;
        #pragma unroll
        for (int q = 0; q < 16; ++q) {
            float4 c = row[q];
            s = fmaf(c.x, c.x, s); s = fmaf(c.y, c.y, s);
            s = fmaf(c.z, c.z, s); s = fmaf(c.w, c.w, s);
        }
        c2[k] = s;
    }
}

// ---------------------------------------------------------------------------
// Fused main: per block = 64 rows. Issues the block's 256KB one-hot ZERO
// stream immediately (depends on nothing -> drains under compute), then
// x load, inputs(NHWC) write, MFMA argmin over 1024 codes (4 waves partition
// K), then quantized(NCHW), the 64 one-hot 1.0 elements, loss partial, hist.
__global__ __launch_bounds__(256, 2) void vq_fused(
    const float* __restrict__ x, const float* __restrict__ cb,
    const _Float16* __restrict__ cbh, const _Float16* __restrict__ cbl,
    const float* __restrict__ c2, float* __restrict__ out,
    int* __restrict__ hist, float* __restrict__ lossPart)
{
    __shared__ float    sb[4][64];
    __shared__ unsigned sk[4][64];
    __shared__ float    ssx[64];
    __shared__ unsigned skf[64];

    const int lane = threadIdx.x & 63;
    const int wid  = threadIdx.x >> 6;
    const int col  = lane & 31;
    const int g    = lane >> 5;
    const int n0   = blockIdx.x * 64;
    const int b    = n0 >> 12;
    const int hw0  = n0 & 4095;
    const size_t bbase = (size_t)b << 18;   // b * D * HWD

    // ---- Phase 0a: issue x loads (lane-coalesced, 16KB/block unique)
    float xv[2][4][8];
    #pragma unroll
    for (int m = 0; m < 2; ++m) {
        const float* xp = x + bbase + (hw0 + m * 32 + col);
        #pragma unroll
        for (int s = 0; s < 4; ++s)
            #pragma unroll
            for (int i = 0; i < 8; ++i)
                xv[m][s][i] = xp[(size_t)(s * 16 + g * 8 + i) << 12];
    }

    // ---- Phase 0b: stream one-hot ZEROS for this block's 64 rows (256KB).
    // Independent of everything; drains under the entire compute phase.
    {
        f32x4 z = {0.f, 0.f, 0.f, 0.f};
        f32x4* eb = reinterpret_cast<f32x4*>(out + O_ENC + (size_t)n0 * K);
        #pragma unroll 8
        for (int i = 0; i < 64; ++i)                 // iter i = row n0+i
            __builtin_nontemporal_store(z, eb + threadIdx.x + i * 256);
    }

    // ---- Phase 0c: inputs (NHWC) from registers (wave 0 holds all 64 rows)
    if (wid == 0) {
        #pragma unroll
        for (int m = 0; m < 2; ++m) {
            float* ip = out + O_INP + (size_t)(n0 + m * 32 + col) * 64 + g * 8;
            #pragma unroll
            for (int s = 0; s < 4; ++s) {
                f32x4 v0 = {xv[m][s][0], xv[m][s][1], xv[m][s][2], xv[m][s][3]};
                f32x4 v1 = {xv[m][s][4], xv[m][s][5], xv[m][s][6], xv[m][s][7]};
                __builtin_nontemporal_store(v0, reinterpret_cast<f32x4*>(ip + s * 16));
                __builtin_nontemporal_store(v1, reinterpret_cast<f32x4*>(ip + s * 16 + 4));
            }
        }
    }

    #pragma unroll
    for (int m = 0; m < 2; ++m) {
        float sp = 0.f;
        #pragma unroll
        for (int s = 0; s < 4; ++s)
            #pragma unroll
            for (int i = 0; i < 8; ++i)
                sp = fmaf(xv[m][s][i], xv[m][s][i], sp);
        sp += __shfl_xor(sp, 32, 64);          // combine g halves
        if (wid == 0 && g == 0) ssx[m * 32 + col] = sp;
    }

    half8 ah[2][4], al[2][4];
    #pragma unroll
    for (int m = 0; m < 2; ++m)
        #pragma unroll
        for (int s = 0; s < 4; ++s)
            #pragma unroll
            for (int i = 0; i < 8; ++i) {
                _Float16 h = (_Float16)xv[m][s][i];
                ah[m][s][i] = h;
                al[m][s][i] = (_Float16)(xv[m][s][i] - (float)h);
            }

    // ---- Phase 1: MFMA argmin. score = ||c||^2 - 2 x.c
    float    best[2][16];
    unsigned kbest[2][16];
    #pragma unroll
    for (int m = 0; m < 2; ++m)
        #pragma unroll
        for (int r = 0; r < 16; ++r) { best[m][r] = 3.4e38f; kbest[m][r] = 0u; }

    const half8* Bh = reinterpret_cast<const half8*>(cbh);
    const half8* Bl = reinterpret_cast<const half8*>(cbl);

    for (int j = 0; j < 8; ++j) {
        int kt = wid * 8 + j;                  // this wave's 32-code tile
        half8 bh[4], bl_[4];
        #pragma unroll
        for (int s = 0; s < 4; ++s) {
            bh[s]  = Bh[(kt * 4 + s) * 64 + lane];   // coalesced, L2-resident
            bl_[s] = Bl[(kt * 4 + s) * 64 + lane];
        }
        float    c2v  = c2[kt * 32 + col];
        unsigned kcur = (unsigned)(kt * 32 + col);

        f32x16 a0, a1;
        #pragma unroll
        for (int r = 0; r < 16; ++r) { a0[r] = 0.f; a1[r] = 0.f; }

        #pragma unroll
        for (int s = 0; s < 4; ++s) {
            a0 = __builtin_amdgcn_mfma_f32_32x32x16_f16(ah[0][s], bh[s],  a0, 0, 0, 0);
            a1 = __builtin_amdgcn_mfma_f32_32x32x16_f16(ah[1][s], bh[s],  a1, 0, 0, 0);
            a0 = __builtin_amdgcn_mfma_f32_32x32x16_f16(al[0][s], bh[s],  a0, 0, 0, 0);
            a1 = __builtin_amdgcn_mfma_f32_32x32x16_f16(al[1][s], bh[s],  a1, 0, 0, 0);
            a0 = __builtin_amdgcn_mfma_f32_32x32x16_f16(ah[0][s], bl_[s], a0, 0, 0, 0);
            a1 = __builtin_amdgcn_mfma_f32_32x32x16_f16(ah[1][s], bl_[s], a1, 0, 0, 0);
        }

        #pragma unroll
        for (int r = 0; r < 16; ++r) {
            float s0 = fmaf(-2.0f, a0[r], c2v);
            if (s0 < best[0][r]) { best[0][r] = s0; kbest[0][r] = kcur; }
            float s1 = fmaf(-2.0f, a1[r], c2v);
            if (s1 < best[1][r]) { best[1][r] = s1; kbest[1][r] = kcur; }
        }
    }

    // Per-wave cross-lane argmin over the 32 cols
    #pragma unroll
    for (int m = 0; m < 2; ++m) {
        #pragma unroll
        for (int r = 0; r < 16; ++r) {
            float bv = best[m][r]; unsigned kv = kbest[m][r];
            #pragma unroll
            for (int mask = 1; mask <= 16; mask <<= 1) {
                float    ob = __shfl_xor(bv, mask);
                unsigned ok = (unsigned)__shfl_xor((int)kv, mask);
                if (ob < bv || (ob == bv && ok < kv)) { bv = ob; kv = ok; }
            }
            if (col == 0) {
                int row = (r & 3) + 8 * (r >> 2) + 4 * g;   // C layout (m74/m101)
                sb[wid][m * 32 + row] = bv;
                sk[wid][m * 32 + row] = kv;
            }
        }
    }
    __syncthreads();

    // ---- Phase 2: cross-wave combine, loss partial, histogram
    if (threadIdx.x < 64) {
        int t = threadIdx.x;
        float bv = sb[0][t]; unsigned kv = sk[0][t];
        #pragma unroll
        for (int w = 1; w < 4; ++w) {
            float ob = sb[w][t];
            if (ob < bv) { bv = ob; kv = sk[w][t]; }
        }
        skf[t] = kv;
        atomicAdd(&hist[kv], 1);
        float lp = bv + ssx[t];                 // ||c-x||^2 = score + ||x||^2
        #pragma unroll
        for (int off = 32; off > 0; off >>= 1) lp += __shfl_down(lp, off, 64);
        if (t == 0) lossPart[blockIdx.x] = lp;
    }
    // Drain this wave's zero-stores before anyone overwrites with 1.0
    asm volatile("s_waitcnt vmcnt(0)" ::: "memory");
    __syncthreads();

    // ---- Phase 3: one-hot 1.0 elements (zeros already streamed)
    if (threadIdx.x < 64) {
        int t = threadIdx.x;
        out[O_ENC + (size_t)(n0 + t) * K + skf[t]] = 1.0f;
    }

    // ---- Phase 4: quantized NCHW. wave w -> 16 channels, lane -> row.
    {
        unsigned kr = skf[lane];
        const float* crow = cb + (size_t)kr * D;
        float* ob = out + O_OUT + bbase + hw0 + lane;
        #pragma unroll
        for (int c16 = 0; c16 < 16; ++c16) {
            int c = wid * 16 + c16;
            __builtin_nontemporal_store(crow[c], ob + ((size_t)c << 12));
        }
    }
}

// ---------------------------------------------------------------------------
// Scalars: perplexity from histogram, loss from 2048 partials
__global__ __launch_bounds__(1024) void final_kernel(
    const int* __restrict__ hist, const float* __restrict__ lossPart,
    float* __restrict__ out)
{
    __shared__ float red[1024];
    int t = threadIdx.x;

    float p = (float)hist[t] * (1.0f / (float)NVEC);
    red[t] = p * logf(p + 1e-10f);
    __syncthreads();
    for (int s = 512; s > 0; s >>= 1) {
        if (t < s) red[t] += red[t + s];
        __syncthreads();
    }
    float perp = expf(-red[0]);
    __syncthreads();

    red[t] = lossPart[t] + lossPart[t + 1024];
    __syncthreads();
    for (int s = 512; s > 0; s >>= 1) {
        if (t < s) red[t] += red[t + s];
        __syncthreads();
    }
    if (t == 0) {
        out[O_PERP] = perp;
        out[O_LOSS] = 0.25f * red[0] / 8388608.0f;
    }
}

// ---------------------------------------------------------------------------
extern "C" void kernel_launch(void* const* d_in, const int* in_sizes, int n_in,
                              void* d_out, int out_size, void* d_ws, size_t ws_size,
                              hipStream_t stream) {
    const float* x  = (const float*)d_in[0];
    const float* cb = (const float*)d_in[1];
    float* out = (float*)d_out;

    char* ws = (char*)d_ws;
    _Float16* cbh   = (_Float16*)(ws + WS_CBH);
    _Float16* cbl   = (_Float16*)(ws + WS_CBL);
    float*    c2    = (float*)(ws + WS_C2);
    int*      hist  = (int*)(ws + WS_HIST);
    float*    lpart = (float*)(ws + WS_LPART);

    (void)hipMemsetAsync(hist, 0, K * sizeof(int), stream);

    prep_kernel<<<36, 256, 0, stream>>>(cb, cbh, cbl, c2);
    vq_fused<<<NVEC / 64, 256, 0, stream>>>(x, cb, cbh, cbl, c2, out, hist, lpart);
    final_kernel<<<1, 1024, 0, stream>>>(hist, lpart, out);
}